// Round 1
// baseline (501.059 us; speedup 1.0000x reference)
//
#include <hip/hip_runtime.h>
#include <stdint.h>

#define D_MODEL 1024
#define NHEADS  16
#define DHEAD   64
#define BATCH   4
#define SEQ     2048
#define MTOT    (BATCH*SEQ)

typedef unsigned short u16;
typedef __bf16 bf16x8 __attribute__((ext_vector_type(8)));
typedef float  f32x4  __attribute__((ext_vector_type(4)));
typedef u16    u16x8  __attribute__((ext_vector_type(8)));
typedef u16    u16x4  __attribute__((ext_vector_type(4)));

__device__ __forceinline__ u16 f2bf(float f) {
  uint32_t u = __builtin_bit_cast(uint32_t, f);
  u += 0x7fff + ((u >> 16) & 1);   // RNE
  return (u16)(u >> 16);
}

__device__ __forceinline__ void gll16(const u16* g, u16* lds) {
  __builtin_amdgcn_global_load_lds(
      (__attribute__((address_space(1))) void*)(g),
      (__attribute__((address_space(3))) void*)(lds), 16, 0, 0);
}

// fp32 -> bf16 elementwise
__global__ void cvtk(const float4* __restrict__ in, u16x4* __restrict__ out, int n4) {
  const int i = blockIdx.x * blockDim.x + threadIdx.x;
  if (i < n4) {
    const float4 f = in[i];
    u16x4 h;
    h[0] = f2bf(f.x); h[1] = f2bf(f.y); h[2] = f2bf(f.z); h[3] = f2bf(f.w);
    out[i] = h;
  }
}

// C = A (MxK, bf16) * B^T (B stored [N][K], bf16)
// MODE 0: natural fp32 store to Cout[M][D_MODEL]
// MODE 1: QKV: grid.z selects W0/W1/W2; bf16 store permuted to [z][B][H][S][DHEAD]; z==0 scaled 0.125
template<int MODE>
__launch_bounds__(256)
__global__ void gemm_bt_k(const u16* __restrict__ A,
                          const u16* __restrict__ W0,
                          const u16* __restrict__ W1,
                          const u16* __restrict__ W2,
                          void* __restrict__ Cout)
{
  constexpr int K = D_MODEL;
  const int tid = threadIdx.x;
  const int l = tid & 63, w = tid >> 6;
  const int m0 = blockIdx.x * 128;
  const int n0 = blockIdx.y * 128;
  const u16* Bm = W0;
  float scale = 1.0f;
  if (MODE == 1) {
    const int z = blockIdx.z;
    Bm = (z == 0) ? W0 : ((z == 1) ? W1 : W2);
    scale = (z == 0) ? 0.125f : 1.0f;
  }

  __shared__ __align__(16) u16 As[128*32];
  __shared__ __align__(16) u16 Bs[128*32];

  f32x4 acc[4][4];
  #pragma unroll
  for (int i = 0; i < 4; ++i)
    #pragma unroll
    for (int j = 0; j < 4; ++j)
      acc[i][j] = f32x4{0.f, 0.f, 0.f, 0.f};

  const int wr = w >> 1, wc = w & 1;
  const int srow = l >> 2;         // 0..15 within segment
  const int scol = (l & 3) * 8;    // k element offset

  for (int k0 = 0; k0 < K; k0 += 32) {
    __syncthreads();
    #pragma unroll
    for (int j = 0; j < 2; ++j) {
      const int seg = w * 2 + j;   // 0..7, each 16 rows
      gll16(A  + (size_t)(m0 + seg*16 + srow) * K + k0 + scol, &As[seg*512]);
      gll16(Bm + (size_t)(n0 + seg*16 + srow) * K + k0 + scol, &Bs[seg*512]);
    }
    __syncthreads();
    bf16x8 af[4], bfr[4];
    #pragma unroll
    for (int m = 0; m < 4; ++m)
      af[m] = *(const bf16x8*)&As[(wr*64 + m*16 + (l & 15))*32 + (l >> 4)*8];
    #pragma unroll
    for (int n = 0; n < 4; ++n)
      bfr[n] = *(const bf16x8*)&Bs[(wc*64 + n*16 + (l & 15))*32 + (l >> 4)*8];
    #pragma unroll
    for (int m = 0; m < 4; ++m)
      #pragma unroll
      for (int n = 0; n < 4; ++n)
        acc[m][n] = __builtin_amdgcn_mfma_f32_16x16x32_bf16(af[m], bfr[n], acc[m][n], 0, 0, 0);
  }

  const int g = l >> 4, c15 = l & 15;
  #pragma unroll
  for (int m = 0; m < 4; ++m) {
    #pragma unroll
    for (int n = 0; n < 4; ++n) {
      #pragma unroll
      for (int j = 0; j < 4; ++j) {
        const int row = m0 + wr*64 + m*16 + g*4 + j;
        const int col = n0 + wc*64 + n*16 + c15;
        const float v = acc[m][n][j] * scale;
        if (MODE == 0) {
          ((float*)Cout)[(size_t)row * D_MODEL + col] = v;
        } else {
          const int b = row >> 11, s = row & (SEQ-1);
          const int h = col >> 6, dh = col & (DHEAD-1);
          ((u16*)Cout)[(size_t)blockIdx.z * MTOT * D_MODEL
                       + ((size_t)(b*NHEADS + h) * SEQ + s) * DHEAD + dh] = f2bf(v);
        }
      }
    }
  }
}

// causal flash attention: Q/K/V in [B*H][S][64] bf16, out att [B*S][D_MODEL] bf16
// grid: x = SEQ/128 q-tiles, y = B*H. 4 waves, each owns 32 q-rows.
__launch_bounds__(256)
__global__ void attn_k(const u16* __restrict__ Qb, const u16* __restrict__ Kb,
                       const u16* __restrict__ Vb, u16* __restrict__ Oa)
{
  const int tid = threadIdx.x;
  const int l = tid & 63, w = tid >> 6;
  const int q0 = blockIdx.x * 128;
  const int bh = blockIdx.y;
  const int b = bh >> 4, h = bh & 15;
  const size_t base = (size_t)bh * SEQ * DHEAD;
  const u16* Q  = Qb + base;
  const u16* Kg = Kb + base;
  const u16* Vg = Vb + base;

  __shared__ __align__(16) u16 Ks[64*64];      // [kv][dh], XOR-swizzled
  __shared__ __align__(16) u16 Vt[64*64];      // [dh][kv], XOR-swizzled
  __shared__ __align__(16) u16 Pl[4][32*64];   // per-wave P, XOR-swizzled

  const int rowbase = q0 + w*32;
  bf16x8 qf[2][2];
  #pragma unroll
  for (int rb = 0; rb < 2; ++rb)
    #pragma unroll
    for (int ks = 0; ks < 2; ++ks)
      qf[rb][ks] = *(const bf16x8*)(Q + (size_t)(rowbase + rb*16 + (l & 15))*DHEAD
                                      + ks*32 + (l >> 4)*8);

  f32x4 o[2][4];
  float mrow[2][4], lrow[2][4];
  #pragma unroll
  for (int rb = 0; rb < 2; ++rb) {
    #pragma unroll
    for (int cb = 0; cb < 4; ++cb) o[rb][cb] = f32x4{0.f,0.f,0.f,0.f};
    #pragma unroll
    for (int j = 0; j < 4; ++j) { mrow[rb][j] = -1e30f; lrow[rb][j] = 0.f; }
  }

  const int ntiles = q0/64 + 2;
  for (int t = 0; t < ntiles; ++t) {
    const int kv0 = t * 64;
    __syncthreads();
    // stage K [64][64] and V^T [64][64]
    #pragma unroll
    for (int it = 0; it < 2; ++it) {
      const int chunk = it*256 + tid;   // 0..511 (16B chunks)
      const int row = chunk >> 3;       // kv row
      const int kc  = chunk & 7;
      const u16x8 dk = *(const u16x8*)(Kg + (size_t)(kv0 + row)*DHEAD + kc*8);
      const int kb = (row*128 + kc*16) ^ ((row & 7) << 4);
      *(u16x8*)((char*)Ks + kb) = dk;
      const u16x8 dv = *(const u16x8*)(Vg + (size_t)(kv0 + row)*DHEAD + kc*8);
      #pragma unroll
      for (int e = 0; e < 8; ++e) {
        const int dh = kc*8 + e;
        const int vb = (dh*128 + row*2) ^ ((dh & 7) << 4);
        *(u16*)((char*)Vt + vb) = dv[e];
      }
    }
    __syncthreads();

    // S = Q K^T  (A-layout rows = q, B-layout cols = kv)
    f32x4 sf[2][4];
    #pragma unroll
    for (int rb = 0; rb < 2; ++rb)
      #pragma unroll
      for (int cn = 0; cn < 4; ++cn) sf[rb][cn] = f32x4{0.f,0.f,0.f,0.f};
    #pragma unroll
    for (int cn = 0; cn < 4; ++cn) {
      const int krow = cn*16 + (l & 15);
      #pragma unroll
      for (int ks = 0; ks < 2; ++ks) {
        const int byt = (krow*128 + ks*64 + (l >> 4)*16) ^ ((krow & 7) << 4);
        const bf16x8 kf = *(const bf16x8*)((char*)Ks + byt);
        #pragma unroll
        for (int rb = 0; rb < 2; ++rb)
          sf[rb][cn] = __builtin_amdgcn_mfma_f32_16x16x32_bf16(qf[rb][ks], kf, sf[rb][cn], 0, 0, 0);
      }
    }

    // causal mask (finite -1e30: no NaN paths; tile 0 always has a real value per row)
    if (kv0 + 63 > rowbase) {
      #pragma unroll
      for (int rb = 0; rb < 2; ++rb)
        #pragma unroll
        for (int cn = 0; cn < 4; ++cn)
          #pragma unroll
          for (int j = 0; j < 4; ++j) {
            const int rowg = rowbase + rb*16 + (l >> 4)*4 + j;
            const int colg = kv0 + cn*16 + (l & 15);
            if (colg > rowg) sf[rb][cn][j] = -1e30f;
          }
    }

    // online softmax (row = rb*16 + (l>>4)*4 + j, 16-lane reductions)
    #pragma unroll
    for (int rb = 0; rb < 2; ++rb) {
      #pragma unroll
      for (int j = 0; j < 4; ++j) {
        float mx = fmaxf(fmaxf(sf[rb][0][j], sf[rb][1][j]), fmaxf(sf[rb][2][j], sf[rb][3][j]));
        mx = fmaxf(mx, __shfl_xor(mx, 1));
        mx = fmaxf(mx, __shfl_xor(mx, 2));
        mx = fmaxf(mx, __shfl_xor(mx, 4));
        mx = fmaxf(mx, __shfl_xor(mx, 8));
        const float mnew = fmaxf(mrow[rb][j], mx);
        const float alpha = __expf(mrow[rb][j] - mnew);
        mrow[rb][j] = mnew;
        float rs = 0.f;
        #pragma unroll
        for (int cn = 0; cn < 4; ++cn) {
          const float p = __expf(sf[rb][cn][j] - mnew);
          sf[rb][cn][j] = p;
          rs += p;
        }
        rs += __shfl_xor(rs, 1);
        rs += __shfl_xor(rs, 2);
        rs += __shfl_xor(rs, 4);
        rs += __shfl_xor(rs, 8);
        lrow[rb][j] = lrow[rb][j]*alpha + rs;
        #pragma unroll
        for (int cb = 0; cb < 4; ++cb) o[rb][cb][j] *= alpha;
      }
    }

    // P (C-layout) -> per-wave LDS -> A-frags
    #pragma unroll
    for (int rb = 0; rb < 2; ++rb)
      #pragma unroll
      for (int cn = 0; cn < 4; ++cn)
        #pragma unroll
        for (int j = 0; j < 4; ++j) {
          const int prow = rb*16 + (l >> 4)*4 + j;
          const int pcol = cn*16 + (l & 15);
          const int byt = (prow*128 + pcol*2) ^ ((prow & 7) << 4);
          *(u16*)((char*)Pl[w] + byt) = f2bf(sf[rb][cn][j]);
        }

    // O += P V
    #pragma unroll
    for (int ks = 0; ks < 2; ++ks) {
      bf16x8 pf[2];
      #pragma unroll
      for (int rb = 0; rb < 2; ++rb) {
        const int prow = rb*16 + (l & 15);
        const int byt = (prow*128 + ks*64 + (l >> 4)*16) ^ ((prow & 7) << 4);
        pf[rb] = *(const bf16x8*)((char*)Pl[w] + byt);
      }
      #pragma unroll
      for (int cb = 0; cb < 4; ++cb) {
        const int vrow = cb*16 + (l & 15);
        const int byt = (vrow*128 + ks*64 + (l >> 4)*16) ^ ((vrow & 7) << 4);
        const bf16x8 vf = *(const bf16x8*)((char*)Vt + byt);
        #pragma unroll
        for (int rb = 0; rb < 2; ++rb)
          o[rb][cb] = __builtin_amdgcn_mfma_f32_16x16x32_bf16(pf[rb], vf, o[rb][cb], 0, 0, 0);
      }
    }
  }

  // normalize + store att in [B*S][D_MODEL] (cols = h*64+dh)
  #pragma unroll
  for (int rb = 0; rb < 2; ++rb)
    #pragma unroll
    for (int cb = 0; cb < 4; ++cb)
      #pragma unroll
      for (int j = 0; j < 4; ++j) {
        const float v = o[rb][cb][j] / lrow[rb][j];
        const int s = rowbase + rb*16 + (l >> 4)*4 + j;
        const int col = h*DHEAD + cb*16 + (l & 15);
        Oa[(size_t)(b*SEQ + s) * D_MODEL + col] = f2bf(v);
      }
}

extern "C" void kernel_launch(void* const* d_in, const int* in_sizes, int n_in,
                              void* d_out, int out_size, void* d_ws, size_t ws_size,
                              hipStream_t stream) {
  const float* X  = (const float*)d_in[0];
  const float* Wq = (const float*)d_in[1];
  const float* Wk = (const float*)d_in[2];
  const float* Wv = (const float*)d_in[3];
  const float* Wo = (const float*)d_in[4];

  u16* xb  = (u16*)d_ws;                              // X bf16         [8192][1024]
  u16* wqb = xb  + (size_t)MTOT*D_MODEL;
  u16* wkb = wqb + (size_t)D_MODEL*D_MODEL;
  u16* wvb = wkb + (size_t)D_MODEL*D_MODEL;
  u16* wob = wvb + (size_t)D_MODEL*D_MODEL;
  u16* qkv = wob + (size_t)D_MODEL*D_MODEL;           // [3][B*H][S][64]
  u16* att = qkv + (size_t)3*MTOT*D_MODEL;            // [8192][1024]

  const int nx4 = MTOT*D_MODEL/4;
  const int nw4 = D_MODEL*D_MODEL/4;
  cvtk<<<nx4/256, 256, 0, stream>>>((const float4*)X,  (u16x4*)xb,  nx4);
  cvtk<<<nw4/256, 256, 0, stream>>>((const float4*)Wq, (u16x4*)wqb, nw4);
  cvtk<<<nw4/256, 256, 0, stream>>>((const float4*)Wk, (u16x4*)wkb, nw4);
  cvtk<<<nw4/256, 256, 0, stream>>>((const float4*)Wv, (u16x4*)wvb, nw4);
  cvtk<<<nw4/256, 256, 0, stream>>>((const float4*)Wo, (u16x4*)wob, nw4);

  dim3 g1(MTOT/128, D_MODEL/128, 3);
  gemm_bt_k<1><<<g1, 256, 0, stream>>>(xb, wqb, wkb, wvb, (void*)qkv);

  dim3 g2(SEQ/128, BATCH*NHEADS, 1);
  attn_k<<<g2, 256, 0, stream>>>(qkv, qkv + (size_t)MTOT*D_MODEL,
                                 qkv + (size_t)2*MTOT*D_MODEL, att);

  dim3 g3(MTOT/128, D_MODEL/128, 1);
  gemm_bt_k<0><<<g3, 256, 0, stream>>>(att, wob, nullptr, nullptr, d_out);
}

// Round 2
// 283.636 us; speedup vs baseline: 1.7666x; 1.7666x over previous
//
#include <hip/hip_runtime.h>
#include <stdint.h>

#define D_MODEL 1024
#define NHEADS  16
#define DHEAD   64
#define BATCH   4
#define SEQ     2048
#define MTOT    (BATCH*SEQ)

typedef unsigned short u16;
typedef uint32_t u32;
typedef __bf16 bf16x8 __attribute__((ext_vector_type(8)));
typedef float  f32x4  __attribute__((ext_vector_type(4)));
typedef u16    u16x8  __attribute__((ext_vector_type(8)));
typedef u16    u16x4  __attribute__((ext_vector_type(4)));
typedef u32    u32x4  __attribute__((ext_vector_type(4)));

__device__ __forceinline__ u16 f2bf(float f) {
  uint32_t u = __builtin_bit_cast(uint32_t, f);
  u += 0x7fff + ((u >> 16) & 1);   // RNE
  return (u16)(u >> 16);
}

__device__ __forceinline__ void gll16(const u16* g, u16* lds) {
  __builtin_amdgcn_global_load_lds(
      (__attribute__((address_space(1))) void*)(g),
      (__attribute__((address_space(3))) void*)(lds), 16, 0, 0);
}

// fp32 -> bf16 elementwise
__global__ void cvtk(const float4* __restrict__ in, u16x4* __restrict__ out, int n4) {
  const int i = blockIdx.x * blockDim.x + threadIdx.x;
  if (i < n4) {
    const float4 f = in[i];
    u16x4 h;
    h[0] = f2bf(f.x); h[1] = f2bf(f.y); h[2] = f2bf(f.z); h[3] = f2bf(f.w);
    out[i] = h;
  }
}

// C = A (MxK, bf16) * B^T (B stored [N][K], bf16)
// MODE 0: fp32 store to Cout[M][D_MODEL]
// MODE 1: QKV: grid.z selects W; bf16 store permuted to [z][B][H][S][DHEAD]; z==0 scaled 0.125*log2e
template<int MODE>
__launch_bounds__(256)
__global__ void gemm_bt_k(const u16* __restrict__ A,
                          const u16* __restrict__ W0,
                          const u16* __restrict__ W1,
                          const u16* __restrict__ W2,
                          void* __restrict__ Cout)
{
  constexpr int K = D_MODEL;
  const int tid = threadIdx.x;
  const int l = tid & 63, w = tid >> 6;
  const int m0 = blockIdx.x * 128;
  const int n0 = blockIdx.y * 128;
  const u16* Bm = W0;
  float scale = 1.0f;
  if (MODE == 1) {
    const int z = blockIdx.z;
    Bm = (z == 0) ? W0 : ((z == 1) ? W1 : W2);
    scale = (z == 0) ? 0.125f * 1.44269504088896f : 1.0f;  // fold log2e into Q
  }

  __shared__ __align__(16) u16 As[128*32];
  __shared__ __align__(16) u16 Bs[128*32];

  f32x4 acc[4][4];
  #pragma unroll
  for (int i = 0; i < 4; ++i)
    #pragma unroll
    for (int j = 0; j < 4; ++j)
      acc[i][j] = f32x4{0.f, 0.f, 0.f, 0.f};

  const int wr = w >> 1, wc = w & 1;
  const int srow = l >> 2;
  const int scol = (l & 3) * 8;

  for (int k0 = 0; k0 < K; k0 += 32) {
    __syncthreads();
    #pragma unroll
    for (int j = 0; j < 2; ++j) {
      const int seg = w * 2 + j;
      gll16(A  + (size_t)(m0 + seg*16 + srow) * K + k0 + scol, &As[seg*512]);
      gll16(Bm + (size_t)(n0 + seg*16 + srow) * K + k0 + scol, &Bs[seg*512]);
    }
    __syncthreads();
    bf16x8 af[4], bfr[4];
    #pragma unroll
    for (int m = 0; m < 4; ++m)
      af[m] = *(const bf16x8*)&As[(wr*64 + m*16 + (l & 15))*32 + (l >> 4)*8];
    #pragma unroll
    for (int n = 0; n < 4; ++n)
      bfr[n] = *(const bf16x8*)&Bs[(wc*64 + n*16 + (l & 15))*32 + (l >> 4)*8];
    #pragma unroll
    for (int m = 0; m < 4; ++m)
      #pragma unroll
      for (int n = 0; n < 4; ++n)
        acc[m][n] = __builtin_amdgcn_mfma_f32_16x16x32_bf16(af[m], bfr[n], acc[m][n], 0, 0, 0);
  }

  const int g = l >> 4, c15 = l & 15;
  #pragma unroll
  for (int m = 0; m < 4; ++m) {
    #pragma unroll
    for (int n = 0; n < 4; ++n) {
      #pragma unroll
      for (int j = 0; j < 4; ++j) {
        const int row = m0 + wr*64 + m*16 + g*4 + j;
        const int col = n0 + wc*64 + n*16 + c15;
        const float v = acc[m][n][j] * scale;
        if (MODE == 0) {
          ((float*)Cout)[(size_t)row * D_MODEL + col] = v;
        } else {
          const int b = row >> 11, s = row & (SEQ-1);
          const int h = col >> 6, dh = col & (DHEAD-1);
          ((u16*)Cout)[(size_t)blockIdx.z * MTOT * D_MODEL
                       + ((size_t)(b*NHEADS + h) * SEQ + s) * DHEAD + dh] = f2bf(v);
        }
      }
    }
  }
}

// ---------------------------------------------------------------------------
// Causal flash attention, swapped-operand form.
// grid = 1024 blocks; block r -> (bh, pair) via XCD-locality swizzle.
// Block processes q-tiles {pair, 31-pair} (64 rows each; 4 waves x 16 rows).
// Per kv-tile (64): S^T = mfma(K,Q) -> lane-local softmax -> register
// redistribution (cvt_pk + shfl) -> PV with V^T staged in swizzled LDS.
// ---------------------------------------------------------------------------
__launch_bounds__(256)
__global__ void attn2_k(const u16* __restrict__ Qb, const u16* __restrict__ Kb,
                        const u16* __restrict__ Vb, u16* __restrict__ Oa)
{
  const int tid = threadIdx.x;
  const int l = tid & 63, w = tid >> 6;
  const int g = l >> 4, q = l & 15;
  const int r = blockIdx.x;
  const int bh   = (r & 7) * 8 + ((r >> 3) & 7);   // bh pinned to one XCD
  const int pairi = r >> 6;                         // 0..15
  const int b = bh >> 4, h = bh & 15;
  const size_t base = (size_t)bh * SEQ * DHEAD;
  const u16* Qg = Qb + base;
  const u16* Kg = Kb + base;
  const u16* Vg = Vb + base;

  __shared__ __align__(16) u16 Vt[2][64*64];   // double-buffered V^T, swizzled

  // staging geometry (per thread: rows rowA and rowA+32, cols kc*8..kc*8+7)
  const int kc = tid & 7, rowA = tid >> 3;      // rowA 0..31
  int vbyt[8];
  #pragma unroll
  for (int e = 0; e < 8; ++e) {
    const int d = kc*8 + e;
    vbyt[e] = ((d*8 + ((rowA >> 3) ^ ((kc ^ e) & 7))) << 4) + ((rowA & 7) << 1);
  }

  for (int half = 0; half < 2; ++half) {
    const int tq = half ? (31 - pairi) : pairi;
    const int qrow0 = tq*64 + w*16;

    bf16x8 qf[2];
    qf[0] = *(const bf16x8*)(Qg + (size_t)(qrow0 + q)*DHEAD + g*8);
    qf[1] = *(const bf16x8*)(Qg + (size_t)(qrow0 + q)*DHEAD + 32 + g*8);

    f32x4 o[4];
    #pragma unroll
    for (int nb = 0; nb < 4; ++nb) o[nb] = f32x4{0.f,0.f,0.f,0.f};
    float mrun = -1e30f, lrun = 0.f;

    const int ntk = tq + 1;

    // prologue: stage kv-tile 0 into buffer 0
    {
      const u16x8 d0 = *(const u16x8*)(Vg + (size_t)rowA*DHEAD + kc*8);
      const u16x8 d1 = *(const u16x8*)(Vg + (size_t)(rowA+32)*DHEAD + kc*8);
      #pragma unroll
      for (int e = 0; e < 8; ++e) {
        *(u16*)((char*)Vt[0] + vbyt[e])        = d0[e];
        *(u16*)((char*)Vt[0] + (vbyt[e] ^ 64)) = d1[e];
      }
    }
    __syncthreads();

    for (int t = 0; t < ntk; ++t) {
      const int kv0 = t*64;
      const int cur = t & 1;
      const bool pf = (t + 1 < ntk);

      // issue V prefetch for t+1 early (write after compute)
      u16x8 v0, v1;
      if (pf) {
        v0 = *(const u16x8*)(Vg + (size_t)(kv0 + 64 + rowA)*DHEAD + kc*8);
        v1 = *(const u16x8*)(Vg + (size_t)(kv0 + 96 + rowA)*DHEAD + kc*8);
      }

      // K frags straight from global (L2-hot) + QK^T (swapped)
      f32x4 st[4];
      #pragma unroll
      for (int kvb = 0; kvb < 4; ++kvb) {
        const u16* kr = Kg + (size_t)(kv0 + kvb*16 + q)*DHEAD + g*8;
        const bf16x8 ka0 = *(const bf16x8*)kr;
        const bf16x8 ka1 = *(const bf16x8*)(kr + 32);
        f32x4 a = f32x4{0.f,0.f,0.f,0.f};
        a = __builtin_amdgcn_mfma_f32_16x16x32_bf16(ka0, qf[0], a, 0, 0, 0);
        a = __builtin_amdgcn_mfma_f32_16x16x32_bf16(ka1, qf[1], a, 0, 0, 0);
        st[kvb] = a;
      }

      // causal mask (diagonal tile only); lane's q-row is q, kv = 16kvb+4g+j
      if (t == ntk - 1) {
        #pragma unroll
        for (int kvb = 0; kvb < 4; ++kvb)
          #pragma unroll
          for (int j = 0; j < 4; ++j)
            if (kvb*16 + g*4 + j > w*16 + q) st[kvb][j] = -1e30f;
      }

      // lane-local online softmax (16 values per lane, one q-row)
      float mx = -1e30f;
      #pragma unroll
      for (int kvb = 0; kvb < 4; ++kvb)
        mx = fmaxf(mx, fmaxf(fmaxf(st[kvb][0], st[kvb][1]),
                             fmaxf(st[kvb][2], st[kvb][3])));
      mx = fmaxf(mx, __shfl_xor(mx, 16));
      mx = fmaxf(mx, __shfl_xor(mx, 32));
      const float mnew = fmaxf(mrun, mx);
      const float alpha = __builtin_amdgcn_exp2f(mrun - mnew);
      mrun = mnew;
      float rs = 0.f;
      #pragma unroll
      for (int kvb = 0; kvb < 4; ++kvb)
        #pragma unroll
        for (int j = 0; j < 4; ++j) {
          const float p = __builtin_amdgcn_exp2f(st[kvb][j] - mnew);
          st[kvb][j] = p;
          rs += p;
        }
      rs += __shfl_xor(rs, 16);
      rs += __shfl_xor(rs, 32);
      lrun = lrun * alpha + rs;

      // pack P to bf16 pairs
      u32 w32[4][2];
      #pragma unroll
      for (int kvb = 0; kvb < 4; ++kvb) {
        asm("v_cvt_pk_bf16_f32 %0, %1, %2" : "=v"(w32[kvb][0]) : "v"(st[kvb][0]), "v"(st[kvb][1]));
        asm("v_cvt_pk_bf16_f32 %0, %1, %2" : "=v"(w32[kvb][1]) : "v"(st[kvb][2]), "v"(st[kvb][3]));
      }

      // redistribute P^T (lane-local kv-slices) -> PV A-frags
      const int s0 = q + ((g & 1) << 5);
      const int s1 = s0 + 16;
      const bool ghi = (g >> 1) != 0;
      u32 paw[2][4];
      #pragma unroll
      for (int c = 0; c < 2; ++c) {
        const u32 lo0 = (u32)__shfl((int)w32[2*c][0], s0);
        const u32 hi0 = (u32)__shfl((int)w32[2*c+1][0], s0);
        const u32 lo1 = (u32)__shfl((int)w32[2*c][1], s0);
        const u32 hi1 = (u32)__shfl((int)w32[2*c+1][1], s0);
        const u32 lo2 = (u32)__shfl((int)w32[2*c][0], s1);
        const u32 hi2 = (u32)__shfl((int)w32[2*c+1][0], s1);
        const u32 lo3 = (u32)__shfl((int)w32[2*c][1], s1);
        const u32 hi3 = (u32)__shfl((int)w32[2*c+1][1], s1);
        paw[c][0] = ghi ? hi0 : lo0;
        paw[c][1] = ghi ? hi1 : lo1;
        paw[c][2] = ghi ? hi2 : lo2;
        paw[c][3] = ghi ? hi3 : lo3;
      }
      bf16x8 pa[2];
      pa[0] = __builtin_bit_cast(bf16x8, u32x4{paw[0][0], paw[0][1], paw[0][2], paw[0][3]});
      pa[1] = __builtin_bit_cast(bf16x8, u32x4{paw[1][0], paw[1][1], paw[1][2], paw[1][3]});

      // write prefetched V tile (other buffer)
      if (pf) {
        char* vt = (char*)Vt[cur ^ 1];
        #pragma unroll
        for (int e = 0; e < 8; ++e) {
          *(u16*)(vt + vbyt[e])        = v0[e];
          *(u16*)(vt + (vbyt[e] ^ 64)) = v1[e];
        }
      }

      // rescale O by alpha (O rows live at q-row = 4g+j)
      float aj[4];
      #pragma unroll
      for (int j = 0; j < 4; ++j) aj[j] = __shfl(alpha, g*4 + j);
      #pragma unroll
      for (int nb = 0; nb < 4; ++nb)
        #pragma unroll
        for (int j = 0; j < 4; ++j) o[nb][j] *= aj[j];

      // O += P V  (V^T b128 reads, conflict-free swizzle)
      #pragma unroll
      for (int nb = 0; nb < 4; ++nb) {
        const int d = nb*16 + q;
        const int Sd = ((d >> 3) ^ (d & 7)) & 7;
        #pragma unroll
        for (int c = 0; c < 2; ++c) {
          const int blk = d*8 + ((4*c + g) ^ Sd);
          const bf16x8 vf = *(const bf16x8*)((char*)Vt[cur] + blk*16);
          o[nb] = __builtin_amdgcn_mfma_f32_16x16x32_bf16(pa[c], vf, o[nb], 0, 0, 0);
        }
      }
      __syncthreads();
    }

    // epilogue: normalize + store (att layout [B*S][D_MODEL])
    const float linv = __builtin_amdgcn_rcpf(lrun);
    float lj[4];
    #pragma unroll
    for (int j = 0; j < 4; ++j) lj[j] = __shfl(linv, g*4 + j);
    #pragma unroll
    for (int nb = 0; nb < 4; ++nb)
      #pragma unroll
      for (int j = 0; j < 4; ++j) {
        const int s = qrow0 + g*4 + j;
        const int col = h*DHEAD + nb*16 + q;
        Oa[(size_t)(b*SEQ + s) * D_MODEL + col] = f2bf(o[nb][j] * lj[j]);
      }
  }
}

extern "C" void kernel_launch(void* const* d_in, const int* in_sizes, int n_in,
                              void* d_out, int out_size, void* d_ws, size_t ws_size,
                              hipStream_t stream) {
  const float* X  = (const float*)d_in[0];
  const float* Wq = (const float*)d_in[1];
  const float* Wk = (const float*)d_in[2];
  const float* Wv = (const float*)d_in[3];
  const float* Wo = (const float*)d_in[4];

  u16* xb  = (u16*)d_ws;
  u16* wqb = xb  + (size_t)MTOT*D_MODEL;
  u16* wkb = wqb + (size_t)D_MODEL*D_MODEL;
  u16* wvb = wkb + (size_t)D_MODEL*D_MODEL;
  u16* wob = wvb + (size_t)D_MODEL*D_MODEL;
  u16* qkv = wob + (size_t)D_MODEL*D_MODEL;   // [3][B*H][S][64]
  u16* att = qkv + (size_t)3*MTOT*D_MODEL;    // [8192][1024]

  const int nx4 = MTOT*D_MODEL/4;
  const int nw4 = D_MODEL*D_MODEL/4;
  cvtk<<<nx4/256, 256, 0, stream>>>((const float4*)X,  (u16x4*)xb,  nx4);
  cvtk<<<nw4/256, 256, 0, stream>>>((const float4*)Wq, (u16x4*)wqb, nw4);
  cvtk<<<nw4/256, 256, 0, stream>>>((const float4*)Wk, (u16x4*)wkb, nw4);
  cvtk<<<nw4/256, 256, 0, stream>>>((const float4*)Wv, (u16x4*)wvb, nw4);
  cvtk<<<nw4/256, 256, 0, stream>>>((const float4*)Wo, (u16x4*)wob, nw4);

  dim3 g1(MTOT/128, D_MODEL/128, 3);
  gemm_bt_k<1><<<g1, 256, 0, stream>>>(xb, wqb, wkb, wvb, (void*)qkv);

  attn2_k<<<1024, 256, 0, stream>>>(qkv, qkv + (size_t)MTOT*D_MODEL,
                                    qkv + (size_t)2*MTOT*D_MODEL, att);

  dim3 g3(MTOT/128, D_MODEL/128, 1);
  gemm_bt_k<0><<<g3, 256, 0, stream>>>(att, wob, nullptr, nullptr, d_out);
}

// Round 3
// 173.080 us; speedup vs baseline: 2.8950x; 1.6388x over previous
//
#include <hip/hip_runtime.h>
#include <stdint.h>

#define D_MODEL 1024
#define NHEADS  16
#define DHEAD   64
#define BATCH   4
#define SEQ     2048
#define MTOT    (BATCH*SEQ)

typedef unsigned short u16;
typedef uint32_t u32;
typedef __bf16 bf16x8 __attribute__((ext_vector_type(8)));
typedef float  f32x4  __attribute__((ext_vector_type(4)));
typedef float  f32x16 __attribute__((ext_vector_type(16)));
typedef u16    u16x8  __attribute__((ext_vector_type(8)));
typedef u16    u16x4  __attribute__((ext_vector_type(4)));
typedef u32    u32x4  __attribute__((ext_vector_type(4)));

__device__ __forceinline__ u16 f2bf(float f) {
  uint32_t u = __builtin_bit_cast(uint32_t, f);
  u += 0x7fff + ((u >> 16) & 1);   // RNE
  return (u16)(u >> 16);
}

__device__ __forceinline__ void gll16(const u16* g, u16* lds) {
  __builtin_amdgcn_global_load_lds(
      (__attribute__((address_space(1))) void*)(g),
      (__attribute__((address_space(3))) void*)(lds), 16, 0, 0);
}

// fp32 -> bf16 elementwise
__global__ void cvtk(const float4* __restrict__ in, u16x4* __restrict__ out, int n4) {
  const int i = blockIdx.x * blockDim.x + threadIdx.x;
  if (i < n4) {
    const float4 f = in[i];
    u16x4 h;
    h[0] = f2bf(f.x); h[1] = f2bf(f.y); h[2] = f2bf(f.z); h[3] = f2bf(f.w);
    out[i] = h;
  }
}

// C = A (MxK, bf16) * B^T (B stored [N][K], bf16)
// MODE 0: fp32 store to Cout[M][D_MODEL]
// MODE 1: QKV: grid.z selects W; bf16 store permuted to [z][B][H][S][DHEAD]; z==0 scaled 0.125*log2e
template<int MODE>
__launch_bounds__(256)
__global__ void gemm_bt_k(const u16* __restrict__ A,
                          const u16* __restrict__ W0,
                          const u16* __restrict__ W1,
                          const u16* __restrict__ W2,
                          void* __restrict__ Cout)
{
  constexpr int K = D_MODEL;
  const int tid = threadIdx.x;
  const int l = tid & 63, w = tid >> 6;
  const int m0 = blockIdx.x * 128;
  const int n0 = blockIdx.y * 128;
  const u16* Bm = W0;
  float scale = 1.0f;
  if (MODE == 1) {
    const int z = blockIdx.z;
    Bm = (z == 0) ? W0 : ((z == 1) ? W1 : W2);
    scale = (z == 0) ? 0.125f * 1.44269504088896f : 1.0f;
  }

  __shared__ __align__(16) u16 As[128*32];
  __shared__ __align__(16) u16 Bs[128*32];

  f32x4 acc[4][4];
  #pragma unroll
  for (int i = 0; i < 4; ++i)
    #pragma unroll
    for (int j = 0; j < 4; ++j)
      acc[i][j] = f32x4{0.f, 0.f, 0.f, 0.f};

  const int wr = w >> 1, wc = w & 1;
  const int srow = l >> 2;
  const int scol = (l & 3) * 8;

  for (int k0 = 0; k0 < K; k0 += 32) {
    __syncthreads();
    #pragma unroll
    for (int j = 0; j < 2; ++j) {
      const int seg = w * 2 + j;
      gll16(A  + (size_t)(m0 + seg*16 + srow) * K + k0 + scol, &As[seg*512]);
      gll16(Bm + (size_t)(n0 + seg*16 + srow) * K + k0 + scol, &Bs[seg*512]);
    }
    __syncthreads();
    bf16x8 af[4], bfr[4];
    #pragma unroll
    for (int m = 0; m < 4; ++m)
      af[m] = *(const bf16x8*)&As[(wr*64 + m*16 + (l & 15))*32 + (l >> 4)*8];
    #pragma unroll
    for (int n = 0; n < 4; ++n)
      bfr[n] = *(const bf16x8*)&Bs[(wc*64 + n*16 + (l & 15))*32 + (l >> 4)*8];
    #pragma unroll
    for (int m = 0; m < 4; ++m)
      #pragma unroll
      for (int n = 0; n < 4; ++n)
        acc[m][n] = __builtin_amdgcn_mfma_f32_16x16x32_bf16(af[m], bfr[n], acc[m][n], 0, 0, 0);
  }

  const int g = l >> 4, c15 = l & 15;
  #pragma unroll
  for (int m = 0; m < 4; ++m) {
    #pragma unroll
    for (int n = 0; n < 4; ++n) {
      #pragma unroll
      for (int j = 0; j < 4; ++j) {
        const int row = m0 + wr*64 + m*16 + g*4 + j;
        const int col = n0 + wc*64 + n*16 + c15;
        const float v = acc[m][n][j] * scale;
        if (MODE == 0) {
          ((float*)Cout)[(size_t)row * D_MODEL + col] = v;
        } else {
          const int b = row >> 11, s = row & (SEQ-1);
          const int h = col >> 6, dh = col & (DHEAD-1);
          ((u16*)Cout)[(size_t)blockIdx.z * MTOT * D_MODEL
                       + ((size_t)(b*NHEADS + h) * SEQ + s) * DHEAD + dh] = f2bf(v);
        }
      }
    }
  }
}

// ---------------------------------------------------------------------------
// Causal flash attention, 8 warps x 32 q-rows, 32x32x16 MFMA, O^T form.
// grid = 256 blocks: block r -> bh = 8*(r&7)+((r>>3)&7) (XCD-pinned),
// pair p = r>>6; processes q-superblocks {p, 7-p} (256 rows each) = 36 kv-tiles.
// Per kv-tile: S^T = mfma(K, Q^T) -> lane-local softmax (q = lane&31) ->
// P^T B-frags via cvt_pk+permlane32_swap -> O^T += mfma(V^T, P^T).
// K staged via global_load_lds w/ pre-swizzled source; V^T scatter-staged,
// chunk-swizzle S(x)=(x^(x>>3))&7 on both. Epilogue transposes O^T via LDS.
// ---------------------------------------------------------------------------
__launch_bounds__(512)
__global__ void attn3_k(const u16* __restrict__ Qb, const u16* __restrict__ Kb_,
                        const u16* __restrict__ Vb_, u16* __restrict__ Oa)
{
  const int tid = threadIdx.x;
  const int w = tid >> 6, l = tid & 63;
  const int q5 = l & 31, hi = l >> 5;
  const int r = blockIdx.x;
  const int bh = (r & 7) * 8 + ((r >> 3) & 7);
  const int pairi = r >> 6;                     // 0..3
  const int b = bh >> 4, h = bh & 15;
  const size_t base = (size_t)bh * SEQ * DHEAD;
  const u16* Qg = Qb + base;
  const u16* Kg = Kb_ + base;
  const u16* Vg = Vb_ + base;

  // 32KB: K bufs [2][4096] | V bufs at +8192 [2][4096]; reused as Ot[8][2048]
  __shared__ __align__(16) u16 smem[16384];

  // V staging coords: thread loads V[row][kc*8..+7]
  const int kc = tid & 7, row = tid >> 3;       // row 0..63
  // K staging: wave w stages chunks 64w..64w+63 (1KB via one gll16)
  const int kr8 = l >> 3;
  const int kkv = 8*w + kr8;                    // kv row this lane sources
  const int kdc = (l & 7) ^ kr8 ^ w;            // pre-swizzled source d-chunk

  int vidx[8];
  #pragma unroll
  for (int e = 0; e < 8; ++e)
    vidx[e] = (8*kc + e)*64 + (((row >> 3) ^ kc ^ e) & 7)*8 + (row & 7);

  for (int half = 0; half < 2; ++half) {
    const int tq = half ? (7 - pairi) : pairi;
    const int q0w = tq*256 + 32*w;
    const int ntk = (tq + 1) * 4;               // block kv-tiles
    const int ntw = (q0w >> 6) + 1;             // this warp's last compute tile + 1

    bf16x8 qf[4];
    #pragma unroll
    for (int s = 0; s < 4; ++s)
      qf[s] = *(const bf16x8*)(Qg + (size_t)(q0w + q5)*DHEAD + 16*s + 8*hi);

    f32x16 c0 = {}, c1 = {};                    // O^T accum, d-blocks 0/1 (cols q=lane&31)
    float mrun = -1e30f, lrun = 0.f;

    // prologue: stage tile 0 -> buf 0
    {
      gll16(Kg + (size_t)kkv*DHEAD + kdc*8, smem + w*512);
      const u16x8 vr0 = *(const u16x8*)(Vg + (size_t)row*DHEAD + kc*8);
      #pragma unroll
      for (int e = 0; e < 8; ++e) smem[8192 + vidx[e]] = vr0[e];
    }
    __syncthreads();

    for (int t = 0; t < ntk; ++t) {
      const int cur = t & 1;
      const bool pf = (t + 1 < ntk);
      u16x8 vr;
      if (pf) {
        vr = *(const u16x8*)(Vg + (size_t)((t+1)*64 + row)*DHEAD + kc*8);
        gll16(Kg + (size_t)((t+1)*64 + kkv)*DHEAD + kdc*8,
              smem + (cur^1)*4096 + w*512);
      }

      if (t < ntw) {
        const u16* Kb = smem + cur*4096;
        const u16* Vv = smem + 8192 + cur*4096;

        // ---- S^T = K * Q^T ----
        f32x16 st[2] = {{}, {}};
        __builtin_amdgcn_s_setprio(1);
        #pragma unroll
        for (int kb = 0; kb < 2; ++kb) {
          #pragma unroll
          for (int s = 0; s < 4; ++s) {
            const int slot = ((2*s + hi) ^ (l & 7) ^ (4*kb) ^ (q5 >> 3)) & 7;
            const bf16x8 kf = *(const bf16x8*)(Kb + (32*kb + q5)*64 + slot*8);
            st[kb] = __builtin_amdgcn_mfma_f32_32x32x16_bf16(kf, qf[s], st[kb], 0, 0, 0);
          }
        }
        __builtin_amdgcn_s_setprio(0);

        // ---- causal mask (warp's diagonal tile only) ----
        if (t == ntw - 1) {
          const int kv0 = t*64;
          #pragma unroll
          for (int kb = 0; kb < 2; ++kb)
            #pragma unroll
            for (int rr = 0; rr < 16; ++rr) {
              const int kvg = kv0 + 32*kb + (rr & 3) + 8*(rr >> 2) + 4*hi;
              if (kvg > q0w + q5) st[kb][rr] = -1e30f;
            }
        }

        // ---- lane-local online softmax (q-row = q5; partner lane l^32) ----
        float mx = -1e30f;
        #pragma unroll
        for (int kb = 0; kb < 2; ++kb)
          #pragma unroll
          for (int rr = 0; rr < 16; ++rr) mx = fmaxf(mx, st[kb][rr]);
        mx = fmaxf(mx, __shfl_xor(mx, 32));
        const float mnew = fmaxf(mrun, mx);
        const float alpha = __builtin_amdgcn_exp2f(mrun - mnew);
        mrun = mnew;
        float rs = 0.f;
        #pragma unroll
        for (int kb = 0; kb < 2; ++kb)
          #pragma unroll
          for (int rr = 0; rr < 16; ++rr) {
            const float p = __builtin_amdgcn_exp2f(st[kb][rr] - mnew);
            st[kb][rr] = p;
            rs += p;
          }
        rs += __shfl_xor(rs, 32);
        lrun = lrun * alpha + rs;
        #pragma unroll
        for (int rr = 0; rr < 16; ++rr) { c0[rr] *= alpha; c1[rr] *= alpha; }

        // ---- P^T -> B-frags: 16 cvt_pk + 8 permlane32_swap ----
        bf16x8 pb[4];
        #pragma unroll
        for (int kb = 0; kb < 2; ++kb) {
          u32 pw[8];
          #pragma unroll
          for (int i = 0; i < 8; ++i) {
            u32 t0;
            asm("v_cvt_pk_bf16_f32 %0, %1, %2"
                : "=v"(t0) : "v"(st[kb][2*i]), "v"(st[kb][2*i+1]));
            pw[i] = t0;
          }
          asm("v_permlane32_swap_b32 %0, %1" : "+v"(pw[0]), "+v"(pw[2]));
          asm("v_permlane32_swap_b32 %0, %1" : "+v"(pw[1]), "+v"(pw[3]));
          asm("v_permlane32_swap_b32 %0, %1" : "+v"(pw[4]), "+v"(pw[6]));
          asm("v_permlane32_swap_b32 %0, %1" : "+v"(pw[5]), "+v"(pw[7]));
          pb[2*kb]   = __builtin_bit_cast(bf16x8, u32x4{pw[0], pw[1], pw[2], pw[3]});
          pb[2*kb+1] = __builtin_bit_cast(bf16x8, u32x4{pw[4], pw[5], pw[6], pw[7]});
        }

        // ---- O^T += V^T * P^T ----
        __builtin_amdgcn_s_setprio(1);
        #pragma unroll
        for (int s = 0; s < 4; ++s) {
          {
            const int slot = ((2*s + hi) ^ (l & 7) ^ (q5 >> 3)) & 7;
            const bf16x8 vf = *(const bf16x8*)(Vv + q5*64 + slot*8);
            c0 = __builtin_amdgcn_mfma_f32_32x32x16_bf16(vf, pb[s], c0, 0, 0, 0);
          }
          {
            const int slot = ((2*s + hi) ^ (l & 7) ^ 4 ^ (q5 >> 3)) & 7;
            const bf16x8 vf = *(const bf16x8*)(Vv + (32 + q5)*64 + slot*8);
            c1 = __builtin_amdgcn_mfma_f32_32x32x16_bf16(vf, pb[s], c1, 0, 0, 0);
          }
        }
        __builtin_amdgcn_s_setprio(0);
      }

      if (pf) {
        u16* Vd = smem + 8192 + (cur^1)*4096;
        #pragma unroll
        for (int e = 0; e < 8; ++e) Vd[vidx[e]] = vr[e];
      }
      __syncthreads();
    }

    // ---- epilogue: normalize (lane-local!), transpose via LDS, store ----
    const float linv = __builtin_amdgcn_rcpf(lrun);
    #pragma unroll
    for (int Ab = 0; Ab < 2; ++Ab)
      #pragma unroll
      for (int rr = 0; rr < 16; ++rr) {
        const int d = 32*Ab + (rr & 3) + 8*(rr >> 2) + 4*hi;
        smem[w*2048 + q5*64 + (((d >> 3) ^ (q5 & 7)) & 7)*8 + (d & 7)] =
            f2bf((Ab ? c1[rr] : c0[rr]) * linv);
      }
    __syncthreads();
    #pragma unroll
    for (int cc = 0; cc < 4; ++cc) {
      const int dchunk = 4*hi + cc;
      const u16x8 vv = *(const u16x8*)&smem[w*2048 + q5*64 + ((dchunk ^ (q5 & 7)) & 7)*8];
      *(u16x8*)(Oa + (size_t)(b*SEQ + q0w + q5)*D_MODEL + h*DHEAD + 32*hi + 8*cc) = vv;
    }
    __syncthreads();
  }
}

extern "C" void kernel_launch(void* const* d_in, const int* in_sizes, int n_in,
                              void* d_out, int out_size, void* d_ws, size_t ws_size,
                              hipStream_t stream) {
  const float* X  = (const float*)d_in[0];
  const float* Wq = (const float*)d_in[1];
  const float* Wk = (const float*)d_in[2];
  const float* Wv = (const float*)d_in[3];
  const float* Wo = (const float*)d_in[4];

  u16* xb  = (u16*)d_ws;
  u16* wqb = xb  + (size_t)MTOT*D_MODEL;
  u16* wkb = wqb + (size_t)D_MODEL*D_MODEL;
  u16* wvb = wkb + (size_t)D_MODEL*D_MODEL;
  u16* wob = wvb + (size_t)D_MODEL*D_MODEL;
  u16* qkv = wob + (size_t)D_MODEL*D_MODEL;   // [3][B*H][S][64]
  u16* att = qkv + (size_t)3*MTOT*D_MODEL;    // [8192][1024]

  const int nx4 = MTOT*D_MODEL/4;
  const int nw4 = D_MODEL*D_MODEL/4;
  cvtk<<<nx4/256, 256, 0, stream>>>((const float4*)X,  (u16x4*)xb,  nx4);
  cvtk<<<nw4/256, 256, 0, stream>>>((const float4*)Wq, (u16x4*)wqb, nw4);
  cvtk<<<nw4/256, 256, 0, stream>>>((const float4*)Wk, (u16x4*)wkb, nw4);
  cvtk<<<nw4/256, 256, 0, stream>>>((const float4*)Wv, (u16x4*)wvb, nw4);
  cvtk<<<nw4/256, 256, 0, stream>>>((const float4*)Wo, (u16x4*)wob, nw4);

  dim3 g1(MTOT/128, D_MODEL/128, 3);
  gemm_bt_k<1><<<g1, 256, 0, stream>>>(xb, wqb, wkb, wvb, (void*)qkv);

  attn3_k<<<256, 512, 0, stream>>>(qkv, qkv + (size_t)MTOT*D_MODEL,
                                   qkv + (size_t)2*MTOT*D_MODEL, att);

  dim3 g3(MTOT/128, D_MODEL/128, 1);
  gemm_bt_k<0><<<g3, 256, 0, stream>>>(att, wob, nullptr, nullptr, d_out);
}